// Round 4
// baseline (360.522 us; speedup 1.0000x reference)
//
#include <hip/hip_runtime.h>

// SymmetricContraction as ONE bf16 MFMA GEMM:
//   t[bc, k] = sum_m P[bc, m] * Uemb[m, k],  P/U over 992 embedded rows:
//     m   0..815 : triples a<=b<=c   P = xa*xb*xc, cols 0..22  = U3sym
//     m 816..951 : pairs  a<=b       P = xa*xb,    cols 23..26 = U2sym
//     m 952..967 : singles w         P = xw,       col  27     = U1
//     m 968..991 : zero pad
//   epilogue: out = sum_k t[k]*w3[k] + sum_k2 t[23+k2]*w2[k2] + t[27]*w1.
// Precision: U split hi+lo bf16 (2 MFMAs, ~fp32 U); P single RNE bf16 via
// v_cvt_pk_bf16_f32 (est abs err ~0.1 << 0.5 tol). fp32 MFMA accum.
// Rounds 0-3 showed the VALU-FMA formulation is floored at ~186us
// (65us VALU floor, LDS-broadcast pipe vs occupancy squeeze); MfmaUtil was
// 0.0 all session. Wave-disjoint sP rows -> ZERO barriers in the k-loop.

#define B_   1024
#define C_   256
#define L_   16
#define E_   10
#define K3_  23
#define K2_  4

#define NM3  816
#define NM2  136
#define MTOT 992
#define NCH  31     // 992/32 chunks of K=32
#define SPSTR 20    // sP row stride in u32 (80B: 16B-aligned, bank-uniform)
#define STSTR 260   // sT row stride in floats

using f32x4   = __attribute__((ext_vector_type(4))) float;
using short8v = __attribute__((ext_vector_type(8))) short;

// ---- compile-time multiset table: P(m) = XX[a]*XX[b]*XX[c], XX[16]=1, XX[17]=0
struct MTab { unsigned char a[MTOT], b[MTOT], c[MTOT]; };
constexpr MTab mkMT() {
  MTab t = {};
  int m = 0;
  for (int a = 0; a < 16; a++)
    for (int b = a; b < 16; b++)
      for (int c = b; c < 16; c++) { t.a[m] = a; t.b[m] = b; t.c[m] = c; ++m; }
  for (int a = 0; a < 16; a++)
    for (int b = a; b < 16; b++) { t.a[m] = a; t.b[m] = b; t.c[m] = 16; ++m; }
  for (int a = 0; a < 16; a++) { t.a[m] = a; t.b[m] = 16; t.c[m] = 16; ++m; }
  while (m < MTOT) { t.a[m] = 17; t.b[m] = 17; t.c[m] = 17; ++m; }
  return t;
}
constexpr MTab MT = mkMT();

// ---------------- prep phase 1: embedded U table rows [MTOT][32] fp32 ----
__global__ void prep1(const float* __restrict__ U3, const float* __restrict__ U2,
                      const float* __restrict__ U1, float* __restrict__ wsRow) {
  int m = blockIdx.x * 256 + threadIdx.x;
  if (m >= MTOT) return;
  float* row = wsRow + m * 32;
  for (int i = 0; i < 32; i++) row[i] = 0.f;
  if (m < NM3) {
    int aa = 0, bb = 0, cc = 0, t = 0;
    for (int a = 0; a < L_; a++)
      for (int b = a; b < L_; b++)
        for (int c = b; c < L_; c++) {
          if (t == m) { aa = a; bb = b; cc = c; }
          t++;
        }
    int pw[6] = {aa, aa, bb, bb, cc, cc};
    int pv[6] = {bb, cc, aa, cc, aa, bb};
    int pi[6] = {cc, bb, cc, aa, bb, aa};
    bool use[6];
    for (int p = 0; p < 6; p++) {
      bool dup = false;
      for (int q = 0; q < p; q++)
        dup = dup || (pw[p] == pw[q] && pv[p] == pv[q] && pi[p] == pi[q]);
      use[p] = !dup;
    }
    for (int k = 0; k < K3_; k++) {
      float s = 0.f;
      for (int p = 0; p < 6; p++)
        if (use[p]) s += U3[((pw[p] * L_ + pv[p]) * L_ + pi[p]) * K3_ + k];
      row[k] = s;
    }
  } else if (m < NM3 + NM2) {
    int pidx = m - NM3, aa = 0, bb = 0, t = 0;
    for (int a = 0; a < L_; a++)
      for (int b = a; b < L_; b++) {
        if (t == pidx) { aa = a; bb = b; }
        t++;
      }
    for (int k2 = 0; k2 < K2_; k2++) {
      float s = U2[(aa * L_ + bb) * K2_ + k2];
      if (aa != bb) s += U2[(bb * L_ + aa) * K2_ + k2];
      row[23 + k2] = s;
    }
  } else if (m < NM3 + NM2 + L_) {
    row[27] = U1[m - NM3 - NM2];
  }
}

// ---------------- prep phase 2: B-fragments (hi/lo bf16, MFMA layout) ----
// frag[ch][kt][part][lane][j]: j=0..7 ascending m; lane: n=lane&15, kg=lane>>4
__global__ void prep2(const float* __restrict__ wsRow, unsigned short* __restrict__ wsFrag) {
  int q = blockIdx.x * 256 + threadIdx.x;
  if (q >= NCH * 2 * 64) return;
  const int lane = q & 63, kt = (q >> 6) & 1, ch = q >> 7;
  unsigned short hi[8], lo[8];
  for (int j = 0; j < 8; j++) {
    int m = ch * 32 + (lane >> 4) * 8 + j;
    int col = kt * 16 + (lane & 15);
    float v = wsRow[m * 32 + col];
    unsigned vb = __float_as_uint(v);
    unsigned short h = (unsigned short)(vb >> 16);        // RTZ bf16 hi
    float l = v - __uint_as_float(((unsigned)h) << 16);   // exact residual
    unsigned short lw = (unsigned short)(__float_as_uint(l) >> 16);
    hi[j] = h; lo[j] = lw;
  }
  unsigned* dst0 = (unsigned*)(wsFrag + ((size_t)((ch * 2 + kt) * 2 + 0) * 64 + lane) * 8);
  unsigned* dst1 = (unsigned*)(wsFrag + ((size_t)((ch * 2 + kt) * 2 + 1) * 64 + lane) * 8);
  for (int p = 0; p < 4; p++) {
    dst0[p] = (unsigned)hi[2 * p] | ((unsigned)hi[2 * p + 1] << 16);
    dst1[p] = (unsigned)lo[2 * p] | ((unsigned)lo[2 * p + 1] << 16);
  }
}

// ---------------- main ----------------
// grid = 1024 blocks (one per b), 256 threads = 4 waves; wave w owns rows
// [w*64, w*64+64) of sP -> no cross-wave deps in the k-loop (0 barriers).
__global__ __launch_bounds__(256, 4) void symcon_kernel(
    const float* __restrict__ x,   // [B,C,L]
    const float* __restrict__ y,   // [B,E]
    const float* __restrict__ W3,  // [E,K3,C]
    const float* __restrict__ W2,  // [E,K2,C]
    const float* __restrict__ W1,  // [E,1,C]
    const unsigned short* __restrict__ wsFrag,
    float* __restrict__ out)       // [B,C]
{
  __shared__ float smem[28 * STSTR];          // 29120 B; sP (20KB) then reused as sT
  unsigned* sP = (unsigned*)smem;             // [256][SPSTR] u32 (bf16 pairs)
  float* sT = smem;                           // [28][STSTR]

  const int tid = threadIdx.x, c = tid, b = blockIdx.x;
  const int lane = tid & 63;

  // x row -> registers (indices all compile-time after unroll)
  float XX[18];
  {
    const float4* xg = (const float4*)(x + ((size_t)b * C_ + c) * L_);
    #pragma unroll
    for (int i = 0; i < 4; i++) {
      float4 v = xg[i];
      XX[i * 4 + 0] = v.x; XX[i * 4 + 1] = v.y;
      XX[i * 4 + 2] = v.z; XX[i * 4 + 3] = v.w;
    }
    XX[16] = 1.f; XX[17] = 0.f;
  }

  const float4* Bg = (const float4*)wsFrag;
  #define BIDX(ch, kt, part) (((ch) * 2 + (kt)) * 2 + (part)) * 64 + lane
  float4 nb00 = Bg[BIDX(0, 0, 0)], nb01 = Bg[BIDX(0, 0, 1)];
  float4 nb10 = Bg[BIDX(0, 1, 0)], nb11 = Bg[BIDX(0, 1, 1)];

  f32x4 acc[4][2];
  #pragma unroll
  for (int rt = 0; rt < 4; rt++)
    #pragma unroll
    for (int kt = 0; kt < 2; kt++) acc[rt][kt] = (f32x4)0.f;

  const int kg = (tid >> 4) & 3;          // lane k-group
  const int wrow = tid & 192;             // wave row base (w*64)

  #pragma unroll
  for (int ch = 0; ch < NCH; ++ch) {
    // ---- P for this thread's row: 32 values -> 16 packed bf16 pairs ----
    unsigned pk[16];
    #pragma unroll
    for (int jp = 0; jp < 16; ++jp) {
      const int m0 = ch * 32 + 2 * jp, m1 = m0 + 1;
      float p0 = XX[MT.a[m0]] * XX[MT.b[m0]] * XX[MT.c[m0]];
      float p1 = XX[MT.a[m1]] * XX[MT.b[m1]] * XX[MT.c[m1]];
      asm("v_cvt_pk_bf16_f32 %0, %1, %2" : "=v"(pk[jp]) : "v"(p0), "v"(p1));
    }
    unsigned* pr = sP + tid * SPSTR;
    *(uint4*)(pr + 0)  = make_uint4(pk[0], pk[1], pk[2], pk[3]);
    *(uint4*)(pr + 4)  = make_uint4(pk[4], pk[5], pk[6], pk[7]);
    *(uint4*)(pr + 8)  = make_uint4(pk[8], pk[9], pk[10], pk[11]);
    *(uint4*)(pr + 12) = make_uint4(pk[12], pk[13], pk[14], pk[15]);

    // consume prefetched B frags; issue next chunk's loads
    float4 b00 = nb00, b01 = nb01, b10 = nb10, b11 = nb11;
    if (ch + 1 < NCH) {
      nb00 = Bg[BIDX(ch + 1, 0, 0)]; nb01 = Bg[BIDX(ch + 1, 0, 1)];
      nb10 = Bg[BIDX(ch + 1, 1, 0)]; nb11 = Bg[BIDX(ch + 1, 1, 1)];
    }
    short8v B00, B01, B10, B11;
    __builtin_memcpy(&B00, &b00, 16); __builtin_memcpy(&B01, &b01, 16);
    __builtin_memcpy(&B10, &b10, 16); __builtin_memcpy(&B11, &b11, 16);

    // ---- A frags from own wave's sP rows; 16 MFMAs ----
    #pragma unroll
    for (int rt = 0; rt < 4; ++rt) {
      const int row = wrow + rt * 16 + (tid & 15);
      short8v A;
      __builtin_memcpy(&A, sP + row * SPSTR + kg * 4, 16);
      acc[rt][0] = __builtin_amdgcn_mfma_f32_16x16x32_bf16(A, B00, acc[rt][0], 0, 0, 0);
      acc[rt][0] = __builtin_amdgcn_mfma_f32_16x16x32_bf16(A, B01, acc[rt][0], 0, 0, 0);
      acc[rt][1] = __builtin_amdgcn_mfma_f32_16x16x32_bf16(A, B10, acc[rt][1], 0, 0, 0);
      acc[rt][1] = __builtin_amdgcn_mfma_f32_16x16x32_bf16(A, B11, acc[rt][1], 0, 0, 0);
    }
  }

  // ---- transpose t to thread-c layout via sT (overlaps sP: one barrier) ----
  __syncthreads();
  #pragma unroll
  for (int rt = 0; rt < 4; ++rt) {
    const int c0 = wrow + rt * 16 + ((tid >> 4) & 3) * 4;  // D rows
    {
      const int k = tid & 15;                               // kt=0 cols 0..15
      *(f32x4*)&sT[k * STSTR + c0] = acc[rt][0];
    }
    if ((tid & 15) < 12) {                                  // kt=1 cols 16..27
      const int k = 16 + (tid & 15);
      *(f32x4*)&sT[k * STSTR + c0] = acc[rt][1];
    }
  }
  // own-wave readback (wave-local columns): no second barrier needed
  float t[28];
  #pragma unroll
  for (int k = 0; k < 28; ++k) t[k] = sT[k * STSTR + tid];

  // ---- epilogue (same contraction as verified fp32 rounds) ----
  float yreg[E_];
  #pragma unroll
  for (int e = 0; e < E_; e++) yreg[e] = y[b * E_ + e];

  float result = 0.f;
  #pragma unroll
  for (int k = 0; k < K3_; k++) {
    const float* w3p = &W3[k * C_ + c];
    float w3k = 0.f;
    #pragma unroll
    for (int e = 0; e < E_; e++) w3k += w3p[e * K3_ * C_] * yreg[e];
    result += t[k] * w3k;
  }
  #pragma unroll
  for (int k2 = 0; k2 < K2_; k2++) {
    const float* w2p = &W2[k2 * C_ + c];
    float w2k = 0.f;
    #pragma unroll
    for (int e = 0; e < E_; e++) w2k += w2p[e * K2_ * C_] * yreg[e];
    result += t[23 + k2] * w2k;
  }
  {
    float w1v = 0.f;
    #pragma unroll
    for (int e = 0; e < E_; e++) w1v += W1[e * C_ + c] * yreg[e];
    result += t[27] * w1v;
  }

  out[(size_t)b * C_ + c] = result;
}

extern "C" void kernel_launch(void* const* d_in, const int* in_sizes, int n_in,
                              void* d_out, int out_size, void* d_ws, size_t ws_size,
                              hipStream_t stream) {
  const float* x  = (const float*)d_in[0];
  const float* y  = (const float*)d_in[1];
  const float* U3 = (const float*)d_in[2];
  const float* U2 = (const float*)d_in[3];
  const float* U1 = (const float*)d_in[4];
  const float* W3 = (const float*)d_in[5];
  const float* W2 = (const float*)d_in[6];
  const float* W1 = (const float*)d_in[7];
  float* out = (float*)d_out;

  float* wsRow = (float*)d_ws;                          // 992*32*4   = 126976 B
  unsigned short* wsFrag = (unsigned short*)(wsRow + MTOT * 32);  // 126976 B

  prep1<<<dim3(4), dim3(256), 0, stream>>>(U3, U2, U1, wsRow);
  prep2<<<dim3(16), dim3(256), 0, stream>>>(wsRow, wsFrag);
  symcon_kernel<<<dim3(B_), dim3(256), 0, stream>>>(
      x, y, W3, W2, W1, wsFrag, out);
}

// Round 6
// 136.726 us; speedup vs baseline: 2.6368x; 2.6368x over previous
//
#include <hip/hip_runtime.h>

// SymmetricContraction as ONE bf16 MFMA GEMM:
//   t[bc, k] = sum_m P[bc, m] * Uemb[m, k] over 992 embedded rows:
//     m   0..815 : triples a<=b<=c   P = xa*xb*xc, cols 0..22  = U3sym
//     m 816..951 : pairs  a<=b       P = xa*xb,    cols 23..26 = U2sym
//     m 952..967 : singles w         P = xw,       col  27     = U1
//     m 968..991 : zero pad
// Precision identical to PASSING round 4 (absmax 2.0 vs threshold 16.64):
// U split hi+lo bf16 (2 MFMAs ~ fp32 U), P single RNE bf16 via
// v_cvt_pk_bf16_f32, fp32 MFMA accumulate.
//
// Round-5 NaN post-mortem: pr/aptr were passed as __restrict__ but BOTH point
// into sP (and alias outright for lanes with (tid>>4)&3==0) -> compiler
// hoisted chunk-0 A-frag ds_reads above the P ds_writes -> uninitialized LDS
// -> NaN. Fix: plain pointers (compiler sees aliasing, keeps order + waits).
// Round-4 lesson kept: CH as template param so MT[] indices are compile-time
// constants; XX/pk/acc stay in VGPRs (round 4: VGPR=64 proved scratch demotion).

#define B_   1024
#define C_   256
#define L_   16
#define E_   10
#define K3_  23
#define K2_  4

#define NM3  816
#define NM2  136
#define MTOT 992
#define NCH  31     // 992/32 chunks of K=32
#define SPSTR 20    // sP row stride in u32 (80B: 16B-aligned, conflict-minimal)
#define STSTR 260   // sT row stride in floats

using f32x4   = __attribute__((ext_vector_type(4))) float;
using short8v = __attribute__((ext_vector_type(8))) short;

__device__ __host__ __forceinline__ constexpr int tri_(int n) { return n * (n + 1) / 2; }
__device__ __host__ __forceinline__ constexpr int tet_(int n) { return n * (n + 1) * (n + 2) / 6; }

// ---- compile-time multiset table: P(m) = XX[a]*XX[b]*XX[c], XX[16]=1, XX[17]=0
struct MTab { unsigned char a[MTOT], b[MTOT], c[MTOT]; };
constexpr MTab mkMT() {
  MTab t = {};
  int m = 0;
  for (int a = 0; a < 16; a++)
    for (int b = a; b < 16; b++)
      for (int c = b; c < 16; c++) { t.a[m] = a; t.b[m] = b; t.c[m] = c; ++m; }
  for (int a = 0; a < 16; a++)
    for (int b = a; b < 16; b++) { t.a[m] = a; t.b[m] = b; t.c[m] = 16; ++m; }
  for (int a = 0; a < 16; a++) { t.a[m] = a; t.b[m] = 16; t.c[m] = 16; ++m; }
  while (m < MTOT) { t.a[m] = 17; t.b[m] = 17; t.c[m] = 17; ++m; }
  return t;
}
constexpr MTab MT = mkMT();

// ---------------- prep (merged): U rows -> hi/lo bf16 B-fragments ----------
// grid = NCH blocks; block ch: threads 0..31 build rows m=32ch+r in LDS
// (closed-form m -> (a,b,c) inversion), threads 0..127 pack fragments.
__global__ void prep_kernel(const float* __restrict__ U3, const float* __restrict__ U2,
                            const float* __restrict__ U1, unsigned short* __restrict__ wsFrag) {
  __shared__ float sRow[32][33];
  const int ch = blockIdx.x;
  const int tid = threadIdx.x;
  if (tid < 32) {
    const int m = ch * 32 + tid;
    for (int i = 0; i < 32; i++) sRow[tid][i] = 0.f;
    if (m < NM3) {
      int ia = 0;
      while (tet_(16) - tet_(16 - (ia + 1)) <= m) ia++;
      int rem = m - (tet_(16) - tet_(16 - ia));
      int ib = ia;
      while (tri_(16 - ia) - tri_(16 - (ib + 1)) <= rem) ib++;
      int ic = ib + (rem - (tri_(16 - ia) - tri_(16 - ib)));
      int pw[6] = {ia, ia, ib, ib, ic, ic};
      int pv[6] = {ib, ic, ia, ic, ia, ib};
      int pi[6] = {ic, ib, ic, ia, ib, ia};
      bool use[6];
      for (int p = 0; p < 6; p++) {
        bool dup = false;
        for (int q = 0; q < p; q++)
          dup = dup || (pw[p] == pw[q] && pv[p] == pv[q] && pi[p] == pi[q]);
        use[p] = !dup;
      }
      for (int k = 0; k < K3_; k++) {
        float s = 0.f;
        for (int p = 0; p < 6; p++)
          if (use[p]) s += U3[((pw[p] * L_ + pv[p]) * L_ + pi[p]) * K3_ + k];
        sRow[tid][k] = s;
      }
    } else if (m < NM3 + NM2) {
      const int pidx = m - NM3;
      int ia = 0;
      while (136 - tri_(16 - (ia + 1)) <= pidx) ia++;
      int ib = ia + (pidx - (136 - tri_(16 - ia)));
      for (int k2 = 0; k2 < K2_; k2++) {
        float s = U2[(ia * L_ + ib) * K2_ + k2];
        if (ia != ib) s += U2[(ib * L_ + ia) * K2_ + k2];
        sRow[tid][23 + k2] = s;
      }
    } else if (m < NM3 + NM2 + L_) {
      sRow[tid][27] = U1[m - NM3 - NM2];
    }
  }
  __syncthreads();
  if (tid < 128) {
    const int lane = tid & 63, kt = (tid >> 6) & 1;
    unsigned short hi[8], lo[8];
    for (int j = 0; j < 8; j++) {
      float v = sRow[(lane >> 4) * 8 + j][kt * 16 + (lane & 15)];
      unsigned vb = __float_as_uint(v);
      unsigned short h = (unsigned short)(vb >> 16);        // RTZ bf16 hi
      float l = v - __uint_as_float(((unsigned)h) << 16);   // exact residual
      hi[j] = h;
      lo[j] = (unsigned short)(__float_as_uint(l) >> 16);
    }
    unsigned* dst0 = (unsigned*)(wsFrag + ((size_t)((ch * 2 + kt) * 2 + 0) * 64 + lane) * 8);
    unsigned* dst1 = (unsigned*)(wsFrag + ((size_t)((ch * 2 + kt) * 2 + 1) * 64 + lane) * 8);
    for (int p = 0; p < 4; p++) {
      dst0[p] = (unsigned)hi[2 * p] | ((unsigned)hi[2 * p + 1] << 16);
      dst1[p] = (unsigned)lo[2 * p] | ((unsigned)lo[2 * p + 1] << 16);
    }
  }
}

// ---------------- main k-loop body, CH as TEMPLATE param ----------------
#define BIDX(ch, kt, part) ((((ch) * 2 + (kt)) * 2 + (part)) * 64 + lane)

// NOTE: pr/aptr are intentionally NOT __restrict__ — they alias inside sP
// (the round-5 NaN). The compiler must keep ds_write(P) -> ds_read(A) order.
template <int CH>
__device__ __forceinline__ void chunk_body(
    const float (&XX)[18], unsigned* pr, const unsigned* aptr,
    const float4* __restrict__ Bg, int lane, float4 (&nb)[4], f32x4 (&acc)[4][2]) {
  // ---- P for this thread's row: 32 values -> 16 packed bf16 pairs ----
  // All MT indices are compile-time constants => XX[] stays in VGPRs.
  #pragma unroll
  for (int g = 0; g < 4; ++g) {
    unsigned pk[4];
    #pragma unroll
    for (int q = 0; q < 4; ++q) {
      const int m0 = CH * 32 + 2 * (g * 4 + q);
      float p0 = XX[MT.a[m0]] * XX[MT.b[m0]] * XX[MT.c[m0]];
      float p1 = XX[MT.a[m0 + 1]] * XX[MT.b[m0 + 1]] * XX[MT.c[m0 + 1]];
      asm("v_cvt_pk_bf16_f32 %0, %1, %2" : "=v"(pk[q]) : "v"(p0), "v"(p1));
    }
    *(uint4*)(pr + 4 * g) = make_uint4(pk[0], pk[1], pk[2], pk[3]);
  }

  // consume prefetched B frags; issue next chunk's loads (L2-resident)
  float4 b00 = nb[0], b01 = nb[1], b10 = nb[2], b11 = nb[3];
  if constexpr (CH + 1 < NCH) {
    nb[0] = Bg[BIDX(CH + 1, 0, 0)];
    nb[1] = Bg[BIDX(CH + 1, 0, 1)];
    nb[2] = Bg[BIDX(CH + 1, 1, 0)];
    nb[3] = Bg[BIDX(CH + 1, 1, 1)];
  }
  short8v B00, B01, B10, B11;
  __builtin_memcpy(&B00, &b00, 16); __builtin_memcpy(&B01, &b01, 16);
  __builtin_memcpy(&B10, &b10, 16); __builtin_memcpy(&B11, &b11, 16);

  // ---- A frags from own wave's sP rows (compile-time rt offsets); 16 MFMAs
  #pragma unroll
  for (int rt = 0; rt < 4; ++rt) {
    short8v A;
    __builtin_memcpy(&A, aptr + rt * 16 * SPSTR, 16);
    acc[rt][0] = __builtin_amdgcn_mfma_f32_16x16x32_bf16(A, B00, acc[rt][0], 0, 0, 0);
    acc[rt][0] = __builtin_amdgcn_mfma_f32_16x16x32_bf16(A, B01, acc[rt][0], 0, 0, 0);
    acc[rt][1] = __builtin_amdgcn_mfma_f32_16x16x32_bf16(A, B10, acc[rt][1], 0, 0, 0);
    acc[rt][1] = __builtin_amdgcn_mfma_f32_16x16x32_bf16(A, B11, acc[rt][1], 0, 0, 0);
  }
}

template <int CH>
struct Loop {
  static __device__ __forceinline__ void run(
      const float (&XX)[18], unsigned* pr, const unsigned* aptr,
      const float4* __restrict__ Bg, int lane, float4 (&nb)[4], f32x4 (&acc)[4][2]) {
    chunk_body<CH>(XX, pr, aptr, Bg, lane, nb, acc);
    Loop<CH + 1>::run(XX, pr, aptr, Bg, lane, nb, acc);
  }
};
template <>
struct Loop<NCH> {
  static __device__ __forceinline__ void run(
      const float (&)[18], unsigned*, const unsigned*,
      const float4* __restrict__, int, float4 (&)[4], f32x4 (&)[4][2]) {}
};

// grid = 1024 blocks (one per b), 256 threads = 4 waves; wave w owns sP rows
// [w*64, w*64+64) -> zero barriers in the k-loop.
__global__ __launch_bounds__(256, 3) void symcon_kernel(
    const float* __restrict__ x,   // [B,C,L]
    const float* __restrict__ y,   // [B,E]
    const float* __restrict__ W3,  // [E,K3,C]
    const float* __restrict__ W2,  // [E,K2,C]
    const float* __restrict__ W1,  // [E,1,C]
    const unsigned short* __restrict__ wsFrag,
    float* __restrict__ out)       // [B,C]
{
  __shared__ float smem[28 * STSTR];          // 29120 B; sP (20KB) reused as sT
  unsigned* sP = (unsigned*)smem;             // [256][SPSTR] u32 (bf16 pairs)
  float* sT = smem;                           // [28][STSTR]

  const int tid = threadIdx.x, c = tid, b = blockIdx.x;
  const int lane = tid & 63;

  // x row -> 18 registers (constant indices only)
  float XX[18];
  {
    const float4* xg = (const float4*)(x + ((size_t)b * C_ + c) * L_);
    #pragma unroll
    for (int i = 0; i < 4; i++) {
      float4 v = xg[i];
      XX[i * 4 + 0] = v.x; XX[i * 4 + 1] = v.y;
      XX[i * 4 + 2] = v.z; XX[i * 4 + 3] = v.w;
    }
    XX[16] = 1.f; XX[17] = 0.f;
  }

  const float4* Bg = (const float4*)wsFrag;
  float4 nb[4];
  nb[0] = Bg[BIDX(0, 0, 0)]; nb[1] = Bg[BIDX(0, 0, 1)];
  nb[2] = Bg[BIDX(0, 1, 0)]; nb[3] = Bg[BIDX(0, 1, 1)];

  f32x4 acc[4][2];
  #pragma unroll
  for (int rt = 0; rt < 4; rt++)
    #pragma unroll
    for (int kt = 0; kt < 2; kt++) acc[rt][kt] = (f32x4)0.f;

  unsigned* pr = sP + tid * SPSTR;
  const unsigned* aptr = sP + ((tid & 192) + (tid & 15)) * SPSTR + ((tid >> 4) & 3) * 4;

  Loop<0>::run(XX, pr, aptr, Bg, lane, nb, acc);

  // ---- transpose t to thread-c layout via sT (one barrier; own-wave cols) ----
  __syncthreads();
  const int wrow = tid & 192;
  #pragma unroll
  for (int rt = 0; rt < 4; ++rt) {
    const int c0 = wrow + rt * 16 + ((tid >> 4) & 3) * 4;  // D rows (bc)
    {
      const int k = tid & 15;                               // kt=0 cols 0..15
      *(f32x4*)&sT[k * STSTR + c0] = acc[rt][0];
    }
    if ((tid & 15) < 12) {                                  // kt=1 cols 16..27
      const int k = 16 + (tid & 15);
      *(f32x4*)&sT[k * STSTR + c0] = acc[rt][1];
    }
  }
  float t[28];
  #pragma unroll
  for (int k = 0; k < 28; ++k) t[k] = sT[k * STSTR + tid];

  // ---- epilogue (verbatim from verified rounds) ----
  float yreg[E_];
  #pragma unroll
  for (int e = 0; e < E_; e++) yreg[e] = y[b * E_ + e];

  float result = 0.f;
  #pragma unroll
  for (int k = 0; k < K3_; k++) {
    const float* w3p = &W3[k * C_ + c];
    float w3k = 0.f;
    #pragma unroll
    for (int e = 0; e < E_; e++) w3k += w3p[e * K3_ * C_] * yreg[e];
    result += t[k] * w3k;
  }
  #pragma unroll
  for (int k2 = 0; k2 < K2_; k2++) {
    const float* w2p = &W2[k2 * C_ + c];
    float w2k = 0.f;
    #pragma unroll
    for (int e = 0; e < E_; e++) w2k += w2p[e * K2_ * C_] * yreg[e];
    result += t[23 + k2] * w2k;
  }
  {
    float w1v = 0.f;
    #pragma unroll
    for (int e = 0; e < E_; e++) w1v += W1[e * C_ + c] * yreg[e];
    result += t[27] * w1v;
  }

  out[(size_t)b * C_ + c] = result;
}

extern "C" void kernel_launch(void* const* d_in, const int* in_sizes, int n_in,
                              void* d_out, int out_size, void* d_ws, size_t ws_size,
                              hipStream_t stream) {
  const float* x  = (const float*)d_in[0];
  const float* y  = (const float*)d_in[1];
  const float* U3 = (const float*)d_in[2];
  const float* U2 = (const float*)d_in[3];
  const float* U1 = (const float*)d_in[4];
  const float* W3 = (const float*)d_in[5];
  const float* W2 = (const float*)d_in[6];
  const float* W1 = (const float*)d_in[7];
  float* out = (float*)d_out;

  unsigned short* wsFrag = (unsigned short*)d_ws;  // NCH*2*2*64*8 u16 = 126976 B

  prep_kernel<<<dim3(NCH), dim3(256), 0, stream>>>(U3, U2, U1, wsFrag);
  symcon_kernel<<<dim3(B_), dim3(256), 0, stream>>>(
      x, y, W3, W2, W1, wsFrag, out);
}